// Round 7
// baseline (101.301 us; speedup 1.0000x reference)
//
#include <hip/hip_runtime.h>
#include <math.h>

#define ALPHA 0.7f
#define BETTA 0.3f
#define EPS   1e-8f

#define BLOCK 256
#define RPT   4                          // rows per thread per tile
#define TILE_ROWS (BLOCK * RPT)          // 1024 rows / tile
#define TILE_F4   (TILE_ROWS * 3 / 4)    // 768 float4 per input per tile
#define NBLOCKS 512                      // persistent blocks (2/CU)

__device__ __forceinline__ void row_contrib(float x1, float y1, float z1,
                                            float x2, float y2, float z2,
                                            float& a0, float& a1, float& a2,
                                            float& ac) {
    float q1 = x1 * x1 + y1 * y1 + z1 * z1;
    float m = (q1 > EPS * EPS) ? 1.0f : 0.0f;
    float inv1 = (q1 > 0.0f) ? rsqrtf(q1) : 0.0f;
    float n1x = x1 * inv1, n1y = y1 * inv1, n1z = z1 * inv1;

    float q2 = x2 * x2 + y2 * y2 + z2 * z2;
    float inv2 = (q2 > 0.0f) ? rsqrtf(q2) : 0.0f;
    float u2x = x2 * inv2, u2y = y2 * inv2, u2z = z2 * inv2;

    float c = n1x * u2x + n1y * u2y + n1z * u2z;
    c = fminf(1.0f, fmaxf(-1.0f, c));
    float sin_a = sqrtf(fmaxf(0.0f, 1.0f - c * c));
    float cm1 = c - 1.0f;

    float d = n1x * x2 + n1y * y2 + n1z * z2;
    float wx = x2 - n1x * d, wy = y2 - n1y * d, wz = z2 - n1z * d;
    float wq = wx * wx + wy * wy + wz * wz;
    float invw = (wq > 0.0f) ? rsqrtf(wq) : 0.0f;
    float n2x = wx * invw, n2y = wy * invw, n2z = wz * invw;

    float s1 = n1x + n1y + n1z;
    float s2 = n2x + n2y + n2z;

    float tax = sin_a * (n2x * s1 - n1x * s2);
    float tay = sin_a * (n2y * s1 - n1y * s2);
    float taz = sin_a * (n2z * s1 - n1z * s2);

    float tbx = cm1 * (n1x * s1 + n2x * s2);
    float tby = cm1 * (n1y * s1 + n2y * s2);
    float tbz = cm1 * (n1z * s1 + n2z * s2);

    a0 += (ALPHA * tax * tax + BETTA * tbx * tbx) * m;
    a1 += (ALPHA * tay * tay + BETTA * tby * tby) * m;
    a2 += (ALPHA * taz * taz + BETTA * tbz * tbz) * m;
    ac += m;
}

// Persistent pipelined reduce: each block owns `iters` consecutive tiles.
// Next tile's coalesced global loads are issued before the barrier so they
// overlap the current tile's compute; regs -> alternate LDS buffer after.
__global__ __launch_bounds__(BLOCK) void trl_reduce(const float* __restrict__ v1,
                                                    const float* __restrict__ v2,
                                                    float4* __restrict__ ws,
                                                    int n_rows, int n_tiles,
                                                    int iters) {
    __shared__ float4 ldsA[2][TILE_F4];  // 2 x 12 KB
    __shared__ float4 ldsB[2][TILE_F4];  // 2 x 12 KB
    __shared__ float smem[4][4];

    int t = threadIdx.x;
    const float4* g1 = (const float4*)v1;
    const float4* g2 = (const float4*)v2;

    long tile0 = (long)blockIdx.x * iters;
    int my_tiles = 0;
    if (tile0 < n_tiles) {
        long rem = (long)n_tiles - tile0;
        my_tiles = (rem < iters) ? (int)rem : iters;
    }

    float a0 = 0.0f, a1 = 0.0f, a2 = 0.0f, ac = 0.0f;
    float4 ra[3], rb[3];

    if (my_tiles > 0) {
        long base = tile0 * TILE_F4;
#pragma unroll
        for (int j = 0; j < 3; ++j) ra[j] = g1[base + j * BLOCK + t];
#pragma unroll
        for (int j = 0; j < 3; ++j) rb[j] = g2[base + j * BLOCK + t];
#pragma unroll
        for (int j = 0; j < 3; ++j) ldsA[0][j * BLOCK + t] = ra[j];
#pragma unroll
        for (int j = 0; j < 3; ++j) ldsB[0][j * BLOCK + t] = rb[j];
    }

    for (int k = 0; k < my_tiles; ++k) {
        int cur = k & 1;
        if (k + 1 < my_tiles) {
            long base = (tile0 + k + 1) * TILE_F4;
#pragma unroll
            for (int j = 0; j < 3; ++j) ra[j] = g1[base + j * BLOCK + t];
#pragma unroll
            for (int j = 0; j < 3; ++j) rb[j] = g2[base + j * BLOCK + t];
        }
        __syncthreads();  // lds[cur] fully staged by all waves

        float4 A0 = ldsA[cur][3 * t + 0];
        float4 A1 = ldsA[cur][3 * t + 1];
        float4 A2 = ldsA[cur][3 * t + 2];
        float4 B0 = ldsB[cur][3 * t + 0];
        float4 B1 = ldsB[cur][3 * t + 1];
        float4 B2 = ldsB[cur][3 * t + 2];

        row_contrib(A0.x, A0.y, A0.z, B0.x, B0.y, B0.z, a0, a1, a2, ac);
        row_contrib(A0.w, A1.x, A1.y, B0.w, B1.x, B1.y, a0, a1, a2, ac);
        row_contrib(A1.z, A1.w, A2.x, B1.z, B1.w, B2.x, a0, a1, a2, ac);
        row_contrib(A2.y, A2.z, A2.w, B2.y, B2.z, B2.w, a0, a1, a2, ac);

        if (k + 1 < my_tiles) {
            int nxt = cur ^ 1;  // safe: all waves passed this iter's barrier,
                                // so no wave still reads buf nxt (iter k-1)
#pragma unroll
            for (int j = 0; j < 3; ++j) ldsA[nxt][j * BLOCK + t] = ra[j];
#pragma unroll
            for (int j = 0; j < 3; ++j) ldsB[nxt][j * BLOCK + t] = rb[j];
        }
    }

    // tail rows beyond the last full tile: block 0, thread-strided scalar
    if (blockIdx.x == 0) {
        for (long r = (long)n_tiles * TILE_ROWS + t; r < n_rows; r += BLOCK) {
            const float* q1 = v1 + r * 3;
            const float* q2 = v2 + r * 3;
            row_contrib(q1[0], q1[1], q1[2], q2[0], q2[1], q2[2], a0, a1, a2, ac);
        }
    }

    // wave-64 shuffle reduction
    for (int off = 32; off > 0; off >>= 1) {
        a0 += __shfl_down(a0, off, 64);
        a1 += __shfl_down(a1, off, 64);
        a2 += __shfl_down(a2, off, 64);
        ac += __shfl_down(ac, off, 64);
    }

    int lane = t & 63;
    int wave = t >> 6;
    __syncthreads();  // done with lds tiles; reuse barrier for smem phase
    if (lane == 0) {
        smem[wave][0] = a0;
        smem[wave][1] = a1;
        smem[wave][2] = a2;
        smem[wave][3] = ac;
    }
    __syncthreads();
    if (t == 0) {
        float4 o;
        o.x = smem[0][0] + smem[1][0] + smem[2][0] + smem[3][0];
        o.y = smem[0][1] + smem[1][1] + smem[2][1] + smem[3][1];
        o.z = smem[0][2] + smem[1][2] + smem[2][2] + smem[3][2];
        o.w = smem[0][3] + smem[1][3] + smem[2][3] + smem[3][3];
        ws[blockIdx.x] = o;
    }
}

// Stage 2: one 256-thread block over the (<=512) float4 partials.
__global__ __launch_bounds__(256) void trl_final(const float4* __restrict__ ws,
                                                 float* __restrict__ out,
                                                 int nblocks) {
    float s0 = 0.0f, s1 = 0.0f, s2 = 0.0f, sc = 0.0f;
    for (int i = threadIdx.x; i < nblocks; i += 256) {
        float4 p = ws[i];
        s0 += p.x; s1 += p.y; s2 += p.z; sc += p.w;
    }
    for (int off = 32; off > 0; off >>= 1) {
        s0 += __shfl_down(s0, off, 64);
        s1 += __shfl_down(s1, off, 64);
        s2 += __shfl_down(s2, off, 64);
        sc += __shfl_down(sc, off, 64);
    }
    __shared__ float smem[4][4];
    int lane = threadIdx.x & 63;
    int wave = threadIdx.x >> 6;
    if (lane == 0) {
        smem[wave][0] = s0;
        smem[wave][1] = s1;
        smem[wave][2] = s2;
        smem[wave][3] = sc;
    }
    __syncthreads();
    if (threadIdx.x < 3) {
        float num = smem[0][threadIdx.x] + smem[1][threadIdx.x] +
                    smem[2][threadIdx.x] + smem[3][threadIdx.x];
        float cnt = smem[0][3] + smem[1][3] + smem[2][3] + smem[3][3];
        cnt = fmaxf(cnt, 1.0f);
        float v = num / cnt;
        if (isnan(v)) v = 0.0f;
        else if (isinf(v)) v = (v > 0.0f) ? 0.1f : -0.1f;
        out[threadIdx.x] = v;
    }
}

extern "C" void kernel_launch(void* const* d_in, const int* in_sizes, int n_in,
                              void* d_out, int out_size, void* d_ws, size_t ws_size,
                              hipStream_t stream) {
    const float* v1 = (const float*)d_in[0];
    const float* v2 = (const float*)d_in[1];
    float* out = (float*)d_out;
    float4* ws = (float4*)d_ws;

    int n_rows = in_sizes[0] / 3;
    int n_tiles = n_rows / TILE_ROWS;           // full tiles only
    int grid = (n_tiles < NBLOCKS) ? (n_tiles > 0 ? n_tiles : 1) : NBLOCKS;
    int iters = (n_tiles + grid - 1) / grid;    // tiles per block (4 @ N=2^21)

    trl_reduce<<<grid, BLOCK, 0, stream>>>(v1, v2, ws, n_rows, n_tiles, iters);
    trl_final<<<1, 256, 0, stream>>>(ws, out, grid);
}

// Round 8
// 94.029 us; speedup vs baseline: 1.0773x; 1.0773x over previous
//
#include <hip/hip_runtime.h>
#include <math.h>

#define ALPHA 0.7f
#define BETTA 0.3f
#define EPS   1e-8f

#define BLOCK 256
#define RPT   4                          // rows per thread
#define TILE_ROWS (BLOCK * RPT)          // 1024 rows / block
#define TILE_F4   (TILE_ROWS * 3 / 4)    // 768 float4 per input per block

// async global->LDS DMA, 16B per lane; LDS dest is wave-uniform base + lane*16
typedef const __attribute__((address_space(1))) void* gas_ptr;
typedef __attribute__((address_space(3))) void* las_ptr;
#define GLOAD_LDS16(gp, lp) \
    __builtin_amdgcn_global_load_lds((gas_ptr)(gp), (las_ptr)(lp), 16, 0, 0)

__device__ __forceinline__ void row_contrib(float x1, float y1, float z1,
                                            float x2, float y2, float z2,
                                            float& a0, float& a1, float& a2,
                                            float& ac) {
    float q1 = x1 * x1 + y1 * y1 + z1 * z1;
    float m = (q1 > EPS * EPS) ? 1.0f : 0.0f;
    float inv1 = (q1 > 0.0f) ? rsqrtf(q1) : 0.0f;
    float n1x = x1 * inv1, n1y = y1 * inv1, n1z = z1 * inv1;

    float q2 = x2 * x2 + y2 * y2 + z2 * z2;
    float inv2 = (q2 > 0.0f) ? rsqrtf(q2) : 0.0f;
    float u2x = x2 * inv2, u2y = y2 * inv2, u2z = z2 * inv2;

    float c = n1x * u2x + n1y * u2y + n1z * u2z;
    c = fminf(1.0f, fmaxf(-1.0f, c));
    float sin_a = sqrtf(fmaxf(0.0f, 1.0f - c * c));
    float cm1 = c - 1.0f;

    float d = n1x * x2 + n1y * y2 + n1z * z2;
    float wx = x2 - n1x * d, wy = y2 - n1y * d, wz = z2 - n1z * d;
    float wq = wx * wx + wy * wy + wz * wz;
    float invw = (wq > 0.0f) ? rsqrtf(wq) : 0.0f;
    float n2x = wx * invw, n2y = wy * invw, n2z = wz * invw;

    float s1 = n1x + n1y + n1z;
    float s2 = n2x + n2y + n2z;

    float tax = sin_a * (n2x * s1 - n1x * s2);
    float tay = sin_a * (n2y * s1 - n1y * s2);
    float taz = sin_a * (n2z * s1 - n1z * s2);

    float tbx = cm1 * (n1x * s1 + n2x * s2);
    float tby = cm1 * (n1y * s1 + n2y * s2);
    float tbz = cm1 * (n1z * s1 + n2z * s2);

    a0 += (ALPHA * tax * tax + BETTA * tbx * tbx) * m;
    a1 += (ALPHA * tay * tay + BETTA * tby * tby) * m;
    a2 += (ALPHA * taz * taz + BETTA * tbz * tbz) * m;
    ac += m;
}

// One-shot blocks (R6 shape — block TLP does the latency hiding), but staging
// via global_load_lds DMA: no VGPR round-trip, no per-load vmcnt stall; the
// single wait is folded into __syncthreads. Epilogue: per-wave shuffle tree
// only; lane0 stores ws[block*4+wave] (no second barrier, no block combine).
__global__ __launch_bounds__(BLOCK) void trl_reduce(const float* __restrict__ v1,
                                                    const float* __restrict__ v2,
                                                    float4* __restrict__ ws,
                                                    int n_rows, int n_tiles) {
    __shared__ float4 ldsA[TILE_F4];  // 12 KB
    __shared__ float4 ldsB[TILE_F4];  // 12 KB

    int t = threadIdx.x;
    int lane = t & 63;
    int w = t >> 6;

    float a0 = 0.0f, a1 = 0.0f, a2 = 0.0f, ac = 0.0f;

    bool full = (blockIdx.x < (unsigned)n_tiles);
    if (full) {
        const float4* g1 = (const float4*)v1;
        const float4* g2 = (const float4*)v2;
        long base = (long)blockIdx.x * TILE_F4;
        int wslot = (w << 6);  // wave-uniform lds offset (in float4)

#pragma unroll
        for (int j = 0; j < 3; ++j)
            GLOAD_LDS16(g1 + base + j * BLOCK + wslot + lane,
                        &ldsA[j * BLOCK + wslot]);
#pragma unroll
        for (int j = 0; j < 3; ++j)
            GLOAD_LDS16(g2 + base + j * BLOCK + wslot + lane,
                        &ldsB[j * BLOCK + wslot]);

        __syncthreads();  // drains DMA (vmcnt) + barrier

        float4 A0 = ldsA[3 * t + 0];
        float4 A1 = ldsA[3 * t + 1];
        float4 A2 = ldsA[3 * t + 2];
        float4 B0 = ldsB[3 * t + 0];
        float4 B1 = ldsB[3 * t + 1];
        float4 B2 = ldsB[3 * t + 2];

        row_contrib(A0.x, A0.y, A0.z, B0.x, B0.y, B0.z, a0, a1, a2, ac);
        row_contrib(A0.w, A1.x, A1.y, B0.w, B1.x, B1.y, a0, a1, a2, ac);
        row_contrib(A1.z, A1.w, A2.x, B1.z, B1.w, B2.x, a0, a1, a2, ac);
        row_contrib(A2.y, A2.z, A2.w, B2.y, B2.z, B2.w, a0, a1, a2, ac);
    }

    // tail rows beyond the last full tile (unused at N=2^21)
    if (blockIdx.x == 0) {
        for (long r = (long)n_tiles * TILE_ROWS + t; r < n_rows; r += BLOCK) {
            const float* q1 = v1 + r * 3;
            const float* q2 = v2 + r * 3;
            row_contrib(q1[0], q1[1], q1[2], q2[0], q2[1], q2[2], a0, a1, a2, ac);
        }
    }

    // per-wave shuffle reduction; one float4 partial per wave
    for (int off = 32; off > 0; off >>= 1) {
        a0 += __shfl_down(a0, off, 64);
        a1 += __shfl_down(a1, off, 64);
        a2 += __shfl_down(a2, off, 64);
        ac += __shfl_down(ac, off, 64);
    }
    if (lane == 0) {
        float4 o;
        o.x = a0; o.y = a1; o.z = a2; o.w = ac;
        ws[(size_t)blockIdx.x * 4 + w] = o;
    }
}

// Stage 2: one 256-thread block over nparts (= grid*4) float4 partials.
__global__ __launch_bounds__(256) void trl_final(const float4* __restrict__ ws,
                                                 float* __restrict__ out,
                                                 int nparts) {
    float s0 = 0.0f, s1 = 0.0f, s2 = 0.0f, sc = 0.0f;
    for (int i = threadIdx.x; i < nparts; i += 256) {
        float4 p = ws[i];
        s0 += p.x; s1 += p.y; s2 += p.z; sc += p.w;
    }
    for (int off = 32; off > 0; off >>= 1) {
        s0 += __shfl_down(s0, off, 64);
        s1 += __shfl_down(s1, off, 64);
        s2 += __shfl_down(s2, off, 64);
        sc += __shfl_down(sc, off, 64);
    }
    __shared__ float smem[4][4];
    int lane = threadIdx.x & 63;
    int wave = threadIdx.x >> 6;
    if (lane == 0) {
        smem[wave][0] = s0;
        smem[wave][1] = s1;
        smem[wave][2] = s2;
        smem[wave][3] = sc;
    }
    __syncthreads();
    if (threadIdx.x < 3) {
        float num = smem[0][threadIdx.x] + smem[1][threadIdx.x] +
                    smem[2][threadIdx.x] + smem[3][threadIdx.x];
        float cnt = smem[0][3] + smem[1][3] + smem[2][3] + smem[3][3];
        cnt = fmaxf(cnt, 1.0f);
        float v = num / cnt;
        if (isnan(v)) v = 0.0f;
        else if (isinf(v)) v = (v > 0.0f) ? 0.1f : -0.1f;
        out[threadIdx.x] = v;
    }
}

extern "C" void kernel_launch(void* const* d_in, const int* in_sizes, int n_in,
                              void* d_out, int out_size, void* d_ws, size_t ws_size,
                              hipStream_t stream) {
    const float* v1 = (const float*)d_in[0];
    const float* v2 = (const float*)d_in[1];
    float* out = (float*)d_out;
    float4* ws = (float4*)d_ws;

    int n_rows = in_sizes[0] / 3;
    int n_tiles = n_rows / TILE_ROWS;   // full tiles (2048 for N=2^21)
    int grid = (n_tiles > 0) ? n_tiles : 1;

    trl_reduce<<<grid, BLOCK, 0, stream>>>(v1, v2, ws, n_rows, n_tiles);
    trl_final<<<1, 256, 0, stream>>>(ws, out, grid * 4);
}

// Round 9
// 87.094 us; speedup vs baseline: 1.1631x; 1.0796x over previous
//
#include <hip/hip_runtime.h>
#include <math.h>

#define ALPHA 0.7f
#define BETTA 0.3f
#define EPS   1e-8f

#define BLOCK 256
#define RPT   4                          // rows per thread
#define TILE_ROWS (BLOCK * RPT)          // 1024 rows / block
#define TILE_F4   (TILE_ROWS * 3 / 4)    // 768 float4 per input per tile
#define TILE_DW   (TILE_ROWS * 3)        // 3072 dwords per input per tile
#define LDS_DW    (TILE_DW + TILE_DW / 12)  // +1 pad dword per 12 -> 3328

__device__ __forceinline__ void row_contrib(float x1, float y1, float z1,
                                            float x2, float y2, float z2,
                                            float& a0, float& a1, float& a2,
                                            float& ac) {
    float q1 = x1 * x1 + y1 * y1 + z1 * z1;
    float m = (q1 > EPS * EPS) ? 1.0f : 0.0f;
    float inv1 = (q1 > 0.0f) ? rsqrtf(q1) : 0.0f;
    float n1x = x1 * inv1, n1y = y1 * inv1, n1z = z1 * inv1;

    float q2 = x2 * x2 + y2 * y2 + z2 * z2;
    float inv2 = (q2 > 0.0f) ? rsqrtf(q2) : 0.0f;
    float u2x = x2 * inv2, u2y = y2 * inv2, u2z = z2 * inv2;

    float c = n1x * u2x + n1y * u2y + n1z * u2z;
    c = fminf(1.0f, fmaxf(-1.0f, c));
    float sin_a = sqrtf(fmaxf(0.0f, 1.0f - c * c));
    float cm1 = c - 1.0f;

    float d = n1x * x2 + n1y * y2 + n1z * z2;
    float wx = x2 - n1x * d, wy = y2 - n1y * d, wz = z2 - n1z * d;
    float wq = wx * wx + wy * wy + wz * wz;
    float invw = (wq > 0.0f) ? rsqrtf(wq) : 0.0f;
    float n2x = wx * invw, n2y = wy * invw, n2z = wz * invw;

    float s1 = n1x + n1y + n1z;
    float s2 = n2x + n2y + n2z;

    float tax = sin_a * (n2x * s1 - n1x * s2);
    float tay = sin_a * (n2y * s1 - n1y * s2);
    float taz = sin_a * (n2z * s1 - n1z * s2);

    float tbx = cm1 * (n1x * s1 + n2x * s2);
    float tby = cm1 * (n1y * s1 + n2y * s2);
    float tbz = cm1 * (n1z * s1 + n2z * s2);

    a0 += (ALPHA * tax * tax + BETTA * tbx * tbx) * m;
    a1 += (ALPHA * tay * tay + BETTA * tby * tby) * m;
    a2 += (ALPHA * taz * taz + BETTA * tbz * tbz) * m;
    ac += m;
}

// Scatter one loaded float4 (logical dword base L0 = 1024*j + 4*t) into the
// padded LDS layout p = L + L/12. One integer divide per float4, then cheap
// carry adjusts for the 4 components.
__device__ __forceinline__ void lds_store_f4(float* lds, int L0, float4 v) {
    int q = L0 / 12;
    int r = L0 - q * 12;            // 0..11, and r%4==0 so r<=8 -> r+3<=11
    int p = L0 + q;                 // physical index of component 0
    lds[p + 0] = v.x;               // r+0..r+3 <= 11: no pad crossing within
    lds[p + 1] = v.y;               // the float4 (since r is a multiple of 4)
    lds[p + 2] = v.z;
    lds[p + 3] = v.w;
}

// R6 structure (one-shot blocks, plain coalesced loads, LDS transpose) with a
// conflict-free padded LDS layout: reads are 12 contiguous dwords at 13*t
// (13 coprime 32 -> 2-way aliasing = free); writes scatter at period-13
// stride (~2-way). Replaces the 8-way-conflicted float4 layout of R6.
__global__ __launch_bounds__(BLOCK) void trl_reduce(const float* __restrict__ v1,
                                                    const float* __restrict__ v2,
                                                    float4* __restrict__ ws,
                                                    int n_rows, int n_tiles) {
    __shared__ float ldsA[LDS_DW];  // 13 KB
    __shared__ float ldsB[LDS_DW];  // 13 KB

    int t = threadIdx.x;
    float a0 = 0.0f, a1 = 0.0f, a2 = 0.0f, ac = 0.0f;

    if (blockIdx.x < (unsigned)n_tiles) {
        const float4* g1 = (const float4*)v1;
        const float4* g2 = (const float4*)v2;
        long base = (long)blockIdx.x * TILE_F4;

        // coalesced: lane i reads base + j*256 + i (unit stride across wave)
        float4 la0 = g1[base + 0 * BLOCK + t];
        float4 la1 = g1[base + 1 * BLOCK + t];
        float4 la2 = g1[base + 2 * BLOCK + t];
        float4 lb0 = g2[base + 0 * BLOCK + t];
        float4 lb1 = g2[base + 1 * BLOCK + t];
        float4 lb2 = g2[base + 2 * BLOCK + t];

        int u = 4 * t;
        lds_store_f4(ldsA, 0 * 1024 + u, la0);
        lds_store_f4(ldsA, 1 * 1024 + u, la1);
        lds_store_f4(ldsA, 2 * 1024 + u, la2);
        lds_store_f4(ldsB, 0 * 1024 + u, lb0);
        lds_store_f4(ldsB, 1 * 1024 + u, lb1);
        lds_store_f4(ldsB, 2 * 1024 + u, lb2);
        __syncthreads();

        // thread t's 4 rows: 12 contiguous padded dwords at 13*t
        float fA[12], fB[12];
        int rb = 13 * t;
#pragma unroll
        for (int k = 0; k < 12; ++k) fA[k] = ldsA[rb + k];
#pragma unroll
        for (int k = 0; k < 12; ++k) fB[k] = ldsB[rb + k];

        row_contrib(fA[0], fA[1], fA[2],  fB[0], fB[1], fB[2],  a0, a1, a2, ac);
        row_contrib(fA[3], fA[4], fA[5],  fB[3], fB[4], fB[5],  a0, a1, a2, ac);
        row_contrib(fA[6], fA[7], fA[8],  fB[6], fB[7], fB[8],  a0, a1, a2, ac);
        row_contrib(fA[9], fA[10], fA[11], fB[9], fB[10], fB[11], a0, a1, a2, ac);
    }

    // tail rows beyond the last full tile (unused at N=2^21)
    if (blockIdx.x == 0) {
        for (long r = (long)n_tiles * TILE_ROWS + t; r < n_rows; r += BLOCK) {
            const float* q1 = v1 + r * 3;
            const float* q2 = v2 + r * 3;
            row_contrib(q1[0], q1[1], q1[2], q2[0], q2[1], q2[2], a0, a1, a2, ac);
        }
    }

    // wave-64 shuffle reduction
    for (int off = 32; off > 0; off >>= 1) {
        a0 += __shfl_down(a0, off, 64);
        a1 += __shfl_down(a1, off, 64);
        a2 += __shfl_down(a2, off, 64);
        ac += __shfl_down(ac, off, 64);
    }

    __shared__ float smem[4][4];
    int lane = t & 63;
    int wave = t >> 6;
    __syncthreads();  // done with lds tiles before smem reuse phase
    if (lane == 0) {
        smem[wave][0] = a0;
        smem[wave][1] = a1;
        smem[wave][2] = a2;
        smem[wave][3] = ac;
    }
    __syncthreads();
    if (t == 0) {
        float4 o;
        o.x = smem[0][0] + smem[1][0] + smem[2][0] + smem[3][0];
        o.y = smem[0][1] + smem[1][1] + smem[2][1] + smem[3][1];
        o.z = smem[0][2] + smem[1][2] + smem[2][2] + smem[3][2];
        o.w = smem[0][3] + smem[1][3] + smem[2][3] + smem[3][3];
        ws[blockIdx.x] = o;
    }
}

// Stage 2: one 256-thread block over the block partials.
__global__ __launch_bounds__(256) void trl_final(const float4* __restrict__ ws,
                                                 float* __restrict__ out,
                                                 int nblocks) {
    float s0 = 0.0f, s1 = 0.0f, s2 = 0.0f, sc = 0.0f;
    for (int i = threadIdx.x; i < nblocks; i += 256) {
        float4 p = ws[i];
        s0 += p.x; s1 += p.y; s2 += p.z; sc += p.w;
    }
    for (int off = 32; off > 0; off >>= 1) {
        s0 += __shfl_down(s0, off, 64);
        s1 += __shfl_down(s1, off, 64);
        s2 += __shfl_down(s2, off, 64);
        sc += __shfl_down(sc, off, 64);
    }
    __shared__ float smem[4][4];
    int lane = threadIdx.x & 63;
    int wave = threadIdx.x >> 6;
    if (lane == 0) {
        smem[wave][0] = s0;
        smem[wave][1] = s1;
        smem[wave][2] = s2;
        smem[wave][3] = sc;
    }
    __syncthreads();
    if (threadIdx.x < 3) {
        float num = smem[0][threadIdx.x] + smem[1][threadIdx.x] +
                    smem[2][threadIdx.x] + smem[3][threadIdx.x];
        float cnt = smem[0][3] + smem[1][3] + smem[2][3] + smem[3][3];
        cnt = fmaxf(cnt, 1.0f);
        float v = num / cnt;
        if (isnan(v)) v = 0.0f;
        else if (isinf(v)) v = (v > 0.0f) ? 0.1f : -0.1f;
        out[threadIdx.x] = v;
    }
}

extern "C" void kernel_launch(void* const* d_in, const int* in_sizes, int n_in,
                              void* d_out, int out_size, void* d_ws, size_t ws_size,
                              hipStream_t stream) {
    const float* v1 = (const float*)d_in[0];
    const float* v2 = (const float*)d_in[1];
    float* out = (float*)d_out;
    float4* ws = (float4*)d_ws;

    int n_rows = in_sizes[0] / 3;
    int n_tiles = n_rows / TILE_ROWS;   // 2048 full tiles for N=2^21
    int grid = (n_tiles > 0) ? n_tiles : 1;

    trl_reduce<<<grid, BLOCK, 0, stream>>>(v1, v2, ws, n_rows, n_tiles);
    trl_final<<<1, 256, 0, stream>>>(ws, out, grid);
}